// Round 5
// baseline (41077.209 us; speedup 1.0000x reference)
//
#include <hip/hip_runtime.h>
#include <math.h>

#define TT 2048
#define BB 64
#define II 64
#define HH 512
#define OO 32
#define OCC 8

// Per-quarter row classes (each quarter = 128 k-rows):
//   rows  0..47  -> VGPR-resident (12 m-groups of 4)   = 384 KB/WG total
//   rows 48..63  -> LDS-resident  (4 m-groups)          = 128 KB/WG
//   rows 64..127 -> streamed from L2/L1 (16 m-groups)   = 512 KB/step
#define VRM 12
#define LDM 4
#define STM 16

// d_out layout: output [T,B,32] | output_ctx [T,B,8] | rate_all [T,B,512]
#define OUT1_OFF ((size_t)TT * BB * OO)
#define RATE_OFF (OUT1_OFF + (size_t)TT * BB * OCC)

// dynamic LDS: wlds[64][512] | st[2][512] | parts[4][512]
#define LDS_W_FLOATS (64 * HH)
#define LDS_FLOATS (LDS_W_FLOATS + 2 * HH + 4 * HH)

// ---------------------------------------------------------------------------
// Pack Wcat[k][h] = Wh[h][k]  (k-major, coalesced in h).
// ---------------------------------------------------------------------------
__global__ __launch_bounds__(256) void pack_weights(
    const float* __restrict__ Wh, float* __restrict__ Wcat)
{
    int idx = blockIdx.x * 256 + threadIdx.x;
    int k = idx >> 9;
    int h = idx & (HH - 1);
    Wcat[idx] = Wh[h * HH + k];
}

// ---------------------------------------------------------------------------
// Prefold: pre[t,b,h] = x[t,b,:] @ Wi[h,:] + bi[h] + bh[h] + NS*noise[t,b,h]
// written INTO the rate region of d_out (scan reads row then overwrites it).
// ---------------------------------------------------------------------------
__global__ __launch_bounds__(512) void prefold(
    const float* __restrict__ x, const float* __restrict__ noise,
    const float* __restrict__ Wi, const float* __restrict__ bi,
    const float* __restrict__ bh, float* __restrict__ pre)
{
    __shared__ float xs[8][II];
    const int tid = threadIdx.x;
    const size_t row0 = (size_t)blockIdx.x * 8;

    const double SIG = 1.5 / sqrt(512.0);
    const float  NS  = (float)sqrt(2.0 * SIG * SIG / 0.1);

    float wi[II];
    #pragma unroll
    for (int k4 = 0; k4 < II / 4; ++k4)
        *(float4*)&wi[4 * k4] = *(const float4*)&Wi[(size_t)tid * II + 4 * k4];
    const float bsum = bi[tid] + bh[tid];

    xs[tid >> 6][tid & 63] = x[(row0 + (tid >> 6)) * II + (tid & 63)];
    __syncthreads();

    #pragma unroll 2
    for (int r = 0; r < 8; ++r) {
        float acc = bsum + NS * noise[(row0 + r) * HH + tid];
        #pragma unroll
        for (int k4 = 0; k4 < II / 4; ++k4) {
            float4 xv = *(const float4*)&xs[r][4 * k4];
            acc += wi[4*k4] * xv.x + wi[4*k4+1] * xv.y
                 + wi[4*k4+2] * xv.z + wi[4*k4+3] * xv.w;
        }
        pre[(row0 + r) * HH + tid] = acc;
    }
}

// ---------------------------------------------------------------------------
// Recurrent scan, resident-weight version. One 512-thread WG per batch.
// Thread: quarter qq = tid>>7 (k-range [128qq,128qq+128)), ht = tid&127
// owns h-columns 4ht..4ht+3 for the dot; owns h = tid for the update.
// Weights: 48 rows/quarter in VGPR, 16 in LDS, 64 streamed per step.
// ---------------------------------------------------------------------------
__global__ __launch_bounds__(512, 2) void rnn_scan5(
    const float* __restrict__ rate0,   // [B,H]
    const float* __restrict__ Wcat,    // [512][512] = Wh^T
    float* __restrict__ pre_rate)      // [T,B,H]: in = pre, out = rate
{
    extern __shared__ float lds[];
    float* wlds  = lds;                     // [64][512]
    float* stbuf = lds + LDS_W_FLOATS;      // [2][512]
    float* parts = stbuf + 2 * HH;          // [4][512]

    const int b    = blockIdx.x;
    const int tid  = threadIdx.x;
    const int qq   = tid >> 7;              // 0..3
    const int ht   = tid & 127;             // h-group: columns 4ht..4ht+3
    const int h4   = 4 * ht;

    // ---- VGPR-resident weights: rows qq*128 + (0..47), cols h4..h4+3
    float4 wreg[VRM][4];
    #pragma unroll
    for (int m = 0; m < VRM; ++m)
        #pragma unroll
        for (int r = 0; r < 4; ++r)
            wreg[m][r] = *(const float4*)&Wcat[(size_t)(qq * 128 + 4 * m + r) * HH + h4];

    // ---- LDS-resident weights: 64 rows; local row R=(qq2,within) <-> k=qq2*128+48+within
    for (int idx = tid; idx < 64 * 128; idx += 512) {
        int rl = idx >> 7;                  // 0..63
        int c4 = (idx & 127) * 4;
        int k  = (rl >> 4) * 128 + 48 + (rl & 15);
        *(float4*)&wlds[rl * HH + c4] = *(const float4*)&Wcat[(size_t)k * HH + c4];
    }

    float rf = rate0[b * HH + tid];
    stbuf[tid] = rf;                        // st[0]
    __syncthreads();

    const float* wstream = Wcat + (size_t)(qq * 128 + 64) * HH + h4;

    for (int t = 0; t < TT; ++t) {
        const int cur = t & 1, nxt = cur ^ 1;
        const size_t row = ((size_t)t * BB + b) * HH;
        const float* stc = stbuf + cur * HH;

        float pre_val = pre_rate[row + tid];   // early; hides under dot

        float a0 = 0.f, a1 = 0.f, a2 = 0.f, a3 = 0.f;

        // ---- streamed rows 64..127 of quarter (64 float4 loads, pipelined)
        #pragma unroll
        for (int sm = 0; sm < STM; ++sm) {
            float4 s4 = *(const float4*)&stc[qq * 128 + 64 + 4 * sm];
            float4 w0 = *(const float4*)(wstream + (size_t)(4 * sm) * HH);
            float4 w1 = *(const float4*)(wstream + (size_t)(4 * sm + 1) * HH);
            float4 w2 = *(const float4*)(wstream + (size_t)(4 * sm + 2) * HH);
            float4 w3 = *(const float4*)(wstream + (size_t)(4 * sm + 3) * HH);
            a0 += w0.x*s4.x + w1.x*s4.y + w2.x*s4.z + w3.x*s4.w;
            a1 += w0.y*s4.x + w1.y*s4.y + w2.y*s4.z + w3.y*s4.w;
            a2 += w0.z*s4.x + w1.z*s4.y + w2.z*s4.z + w3.z*s4.w;
            a3 += w0.w*s4.x + w1.w*s4.y + w2.w*s4.z + w3.w*s4.w;
        }

        // ---- VGPR rows 0..47
        #pragma unroll
        for (int m = 0; m < VRM; ++m) {
            float4 s4 = *(const float4*)&stc[qq * 128 + 4 * m];
            a0 += wreg[m][0].x*s4.x + wreg[m][1].x*s4.y + wreg[m][2].x*s4.z + wreg[m][3].x*s4.w;
            a1 += wreg[m][0].y*s4.x + wreg[m][1].y*s4.y + wreg[m][2].y*s4.z + wreg[m][3].y*s4.w;
            a2 += wreg[m][0].z*s4.x + wreg[m][1].z*s4.y + wreg[m][2].z*s4.z + wreg[m][3].z*s4.w;
            a3 += wreg[m][0].w*s4.x + wreg[m][1].w*s4.y + wreg[m][2].w*s4.z + wreg[m][3].w*s4.w;
        }

        // ---- LDS rows 48..63 (local rows qq*16 + 0..15)
        #pragma unroll
        for (int lm = 0; lm < LDM; ++lm) {
            float4 s4 = *(const float4*)&stc[qq * 128 + 48 + 4 * lm];
            const float* wl = &wlds[(qq * 16 + 4 * lm) * HH + h4];
            float4 w0 = *(const float4*)(wl);
            float4 w1 = *(const float4*)(wl + HH);
            float4 w2 = *(const float4*)(wl + 2 * HH);
            float4 w3 = *(const float4*)(wl + 3 * HH);
            a0 += w0.x*s4.x + w1.x*s4.y + w2.x*s4.z + w3.x*s4.w;
            a1 += w0.y*s4.x + w1.y*s4.y + w2.y*s4.z + w3.y*s4.w;
            a2 += w0.z*s4.x + w1.z*s4.y + w2.z*s4.z + w3.z*s4.w;
            a3 += w0.w*s4.x + w1.w*s4.y + w2.w*s4.z + w3.w*s4.w;
        }

        *(float4*)&parts[qq * HH + h4] = make_float4(a0, a1, a2, a3);
        __syncthreads();                    // parts complete; st[cur] reads done

        // ---- reduce + update: thread tid owns h = tid
        float sum = parts[tid] + parts[HH + tid] + parts[2 * HH + tid] + parts[3 * HH + tid];
        float pre = sum + pre_val;
        rf = 0.9f * rf + 0.1f * tanhf(pre);
        pre_rate[row + tid] = rf;           // overwrite pre with rate
        stbuf[nxt * HH + tid] = rf;
        __syncthreads();                    // st[nxt] ready; parts reads done
    }
}

// ---------------------------------------------------------------------------
// Readouts: 8 rows per 256-thread block, rows staged in LDS, float4 dots.
// ---------------------------------------------------------------------------
__global__ __launch_bounds__(256) void readout(
    const float* __restrict__ rate_all,
    const float* __restrict__ Wo,  const float* __restrict__ bo,
    const float* __restrict__ Woc, const float* __restrict__ boc,
    float* __restrict__ out, float* __restrict__ outc)
{
    __shared__ float rbuf[8][HH];
    const int tid  = threadIdx.x;
    const size_t row0 = (size_t)blockIdx.x * 8;

    for (int i = tid; i < 8 * (HH / 4); i += 256) {
        int r = i >> 7, c = (i & 127) * 4;
        *(float4*)&rbuf[r][c] = *(const float4*)&rate_all[(row0 + r) * HH + c];
    }
    __syncthreads();

    {
        int r = tid >> 5, o = tid & 31;
        const float* w = Wo + (size_t)o * HH;
        float acc = 0.f;
        #pragma unroll 4
        for (int h = 0; h < HH; h += 4) {
            float4 rv = *(const float4*)&rbuf[r][h];
            float4 wv = *(const float4*)&w[h];
            acc += rv.x * wv.x + rv.y * wv.y + rv.z * wv.z + rv.w * wv.w;
        }
        out[(row0 + r) * OO + o] = acc + bo[o];
    }
    if (tid < 64) {
        int r = tid >> 3, oc = tid & 7;
        const float* w = Woc + (size_t)oc * HH;
        float acc = 0.f;
        #pragma unroll 4
        for (int h = 0; h < HH; h += 4) {
            float4 rv = *(const float4*)&rbuf[r][h];
            float4 wv = *(const float4*)&w[h];
            acc += rv.x * wv.x + rv.y * wv.y + rv.z * wv.z + rv.w * wv.w;
        }
        outc[(row0 + r) * OCC + oc] = acc + boc[oc];
    }
}

// ---------------------------------------------------------------------------
extern "C" void kernel_launch(void* const* d_in, const int* in_sizes, int n_in,
                              void* d_out, int out_size, void* d_ws, size_t ws_size,
                              hipStream_t stream)
{
    const float* x     = (const float*)d_in[0];
    const float* rate0 = (const float*)d_in[1];
    const float* noise = (const float*)d_in[2];
    const float* Wi    = (const float*)d_in[3];
    const float* bi    = (const float*)d_in[4];
    const float* Wh    = (const float*)d_in[5];
    const float* bh    = (const float*)d_in[6];
    const float* Wo    = (const float*)d_in[7];
    const float* bo    = (const float*)d_in[8];
    const float* Woc   = (const float*)d_in[9];
    const float* boc   = (const float*)d_in[10];

    float* out   = (float*)d_out;
    float* rateb = out + RATE_OFF;          // pre, then rate
    float* Wcat  = (float*)d_ws;            // 512*512 fp32 = 1 MB

    static int attr_set = 0;                // idempotent, value-deterministic
    if (!attr_set) {
        hipFuncSetAttribute((const void*)rnn_scan5,
                            hipFuncAttributeMaxDynamicSharedMemorySize,
                            LDS_FLOATS * sizeof(float));
        attr_set = 1;
    }

    pack_weights<<<HH * HH / 256, 256, 0, stream>>>(Wh, Wcat);
    prefold<<<TT * BB / 8, 512, 0, stream>>>(x, noise, Wi, bi, bh, rateb);
    rnn_scan5<<<BB, 512, LDS_FLOATS * sizeof(float), stream>>>(rate0, Wcat, rateb);
    readout<<<TT * BB / 8, 256, 0, stream>>>(rateb, Wo, bo, Woc, boc,
                                             out, out + OUT1_OFF);
}

// Round 6
// 13320.506 us; speedup vs baseline: 3.0838x; 3.0838x over previous
//
#include <hip/hip_runtime.h>
#include <math.h>

#define TT 2048
#define BB 64
#define II 64
#define HH 512
#define OO 32
#define OCC 8

// Per-quarter row classes (each quarter = 128 k-rows):
//   rows  0..39  -> VGPR-resident (VRM=10 m-groups of 4) = 160 regs/thread
//   rows 40..55  -> LDS-resident  (LDM=4 m-groups)        = 128 KB/WG
//   rows 56..127 -> streamed from L2/L1 (STM=18 m-groups) = 576 KB/step
#define VRM 10
#define LDM 4
#define STM 18

// d_out layout: output [T,B,32] | output_ctx [T,B,8] | rate_all [T,B,512]
#define OUT1_OFF ((size_t)TT * BB * OO)
#define RATE_OFF (OUT1_OFF + (size_t)TT * BB * OCC)

// dynamic LDS: wlds[64][512] | st[2][512] | parts[4][512]
#define LDS_W_FLOATS (64 * HH)
#define LDS_FLOATS (LDS_W_FLOATS + 2 * HH + 4 * HH)

// ---------------------------------------------------------------------------
// Pack Wcat[k][h] = Wh[h][k]  (k-major, coalesced in h).
// ---------------------------------------------------------------------------
__global__ __launch_bounds__(256) void pack_weights(
    const float* __restrict__ Wh, float* __restrict__ Wcat)
{
    int idx = blockIdx.x * 256 + threadIdx.x;
    int k = idx >> 9;
    int h = idx & (HH - 1);
    Wcat[idx] = Wh[h * HH + k];
}

// ---------------------------------------------------------------------------
// Prefold: pre[t,b,h] = x[t,b,:] @ Wi[h,:] + bi[h] + bh[h] + NS*noise[t,b,h]
// written INTO the rate region of d_out (scan reads row then overwrites it).
// ---------------------------------------------------------------------------
__global__ __launch_bounds__(512) void prefold(
    const float* __restrict__ x, const float* __restrict__ noise,
    const float* __restrict__ Wi, const float* __restrict__ bi,
    const float* __restrict__ bh, float* __restrict__ pre)
{
    __shared__ float xs[8][II];
    const int tid = threadIdx.x;
    const size_t row0 = (size_t)blockIdx.x * 8;

    const double SIG = 1.5 / sqrt(512.0);
    const float  NS  = (float)sqrt(2.0 * SIG * SIG / 0.1);

    float wi[II];
    #pragma unroll
    for (int k4 = 0; k4 < II / 4; ++k4)
        *(float4*)&wi[4 * k4] = *(const float4*)&Wi[(size_t)tid * II + 4 * k4];
    const float bsum = bi[tid] + bh[tid];

    xs[tid >> 6][tid & 63] = x[(row0 + (tid >> 6)) * II + (tid & 63)];
    __syncthreads();

    #pragma unroll 2
    for (int r = 0; r < 8; ++r) {
        float acc = bsum + NS * noise[(row0 + r) * HH + tid];
        #pragma unroll
        for (int k4 = 0; k4 < II / 4; ++k4) {
            float4 xv = *(const float4*)&xs[r][4 * k4];
            acc += wi[4*k4] * xv.x + wi[4*k4+1] * xv.y
                 + wi[4*k4+2] * xv.z + wi[4*k4+3] * xv.w;
        }
        pre[(row0 + r) * HH + tid] = acc;
    }
}

// ---------------------------------------------------------------------------
// Recurrent scan, resident-weight version. One 512-thread WG per batch.
// Thread: quarter qq = tid>>7 (k-range [128qq,128qq+128)), ht = tid&127
// owns h-columns 4ht..4ht+3 for the dot; owns h = tid for the update.
// Weights: 40 rows/quarter in VGPR, 16 in LDS, 72 streamed per step.
// launch_bounds(512,1): do NOT constrain VGPRs below 256 (round-5 spill).
// ---------------------------------------------------------------------------
__global__ __launch_bounds__(512, 1) void rnn_scan6(
    const float* __restrict__ rate0,   // [B,H]
    const float* __restrict__ Wcat,    // [512][512] = Wh^T
    float* __restrict__ pre_rate)      // [T,B,H]: in = pre, out = rate
{
    extern __shared__ float lds[];
    float* wlds  = lds;                     // [64][512]
    float* stbuf = lds + LDS_W_FLOATS;      // [2][512]
    float* parts = stbuf + 2 * HH;          // [4][512]

    const int b    = blockIdx.x;
    const int tid  = threadIdx.x;
    const int qq   = tid >> 7;              // 0..3
    const int ht   = tid & 127;             // h-group: columns 4ht..4ht+3
    const int h4   = 4 * ht;

    // ---- VGPR-resident weights: rows qq*128 + (0..39), cols h4..h4+3
    float4 wreg[VRM][4];
    #pragma unroll
    for (int m = 0; m < VRM; ++m)
        #pragma unroll
        for (int r = 0; r < 4; ++r)
            wreg[m][r] = *(const float4*)&Wcat[(size_t)(qq * 128 + 4 * m + r) * HH + h4];

    // ---- LDS-resident weights: 64 rows; local row rl <-> k=(rl>>4)*128+40+(rl&15)
    for (int idx = tid; idx < 64 * 128; idx += 512) {
        int rl = idx >> 7;                  // 0..63
        int c4 = (idx & 127) * 4;
        int k  = (rl >> 4) * 128 + 40 + (rl & 15);
        *(float4*)&wlds[rl * HH + c4] = *(const float4*)&Wcat[(size_t)k * HH + c4];
    }

    float rf = rate0[b * HH + tid];
    stbuf[tid] = rf;                        // st[0]
    __syncthreads();

    const float* wstream = Wcat + (size_t)(qq * 128 + 56) * HH + h4;

    for (int t = 0; t < TT; ++t) {
        const int cur = t & 1, nxt = cur ^ 1;
        const size_t row = ((size_t)t * BB + b) * HH;
        const float* stc = stbuf + cur * HH;

        float pre_val = pre_rate[row + tid];   // early; hides under dot

        float a0 = 0.f, a1 = 0.f, a2 = 0.f, a3 = 0.f;

        // ---- streamed rows 56..127 of quarter (72 rows; unroll capped to
        // bound in-flight load registers -- round-5 spill lesson)
        #pragma unroll 3
        for (int sm = 0; sm < STM; ++sm) {
            float4 s4 = *(const float4*)&stc[qq * 128 + 56 + 4 * sm];
            float4 w0 = *(const float4*)(wstream + (size_t)(4 * sm) * HH);
            float4 w1 = *(const float4*)(wstream + (size_t)(4 * sm + 1) * HH);
            float4 w2 = *(const float4*)(wstream + (size_t)(4 * sm + 2) * HH);
            float4 w3 = *(const float4*)(wstream + (size_t)(4 * sm + 3) * HH);
            a0 += w0.x*s4.x + w1.x*s4.y + w2.x*s4.z + w3.x*s4.w;
            a1 += w0.y*s4.x + w1.y*s4.y + w2.y*s4.z + w3.y*s4.w;
            a2 += w0.z*s4.x + w1.z*s4.y + w2.z*s4.z + w3.z*s4.w;
            a3 += w0.w*s4.x + w1.w*s4.y + w2.w*s4.z + w3.w*s4.w;
        }

        // ---- VGPR rows 0..39
        #pragma unroll
        for (int m = 0; m < VRM; ++m) {
            float4 s4 = *(const float4*)&stc[qq * 128 + 4 * m];
            a0 += wreg[m][0].x*s4.x + wreg[m][1].x*s4.y + wreg[m][2].x*s4.z + wreg[m][3].x*s4.w;
            a1 += wreg[m][0].y*s4.x + wreg[m][1].y*s4.y + wreg[m][2].y*s4.z + wreg[m][3].y*s4.w;
            a2 += wreg[m][0].z*s4.x + wreg[m][1].z*s4.y + wreg[m][2].z*s4.z + wreg[m][3].z*s4.w;
            a3 += wreg[m][0].w*s4.x + wreg[m][1].w*s4.y + wreg[m][2].w*s4.z + wreg[m][3].w*s4.w;
        }

        // ---- LDS rows 40..55 (local rows qq*16 + 0..15)
        #pragma unroll
        for (int lm = 0; lm < LDM; ++lm) {
            float4 s4 = *(const float4*)&stc[qq * 128 + 40 + 4 * lm];
            const float* wl = &wlds[(qq * 16 + 4 * lm) * HH + h4];
            float4 w0 = *(const float4*)(wl);
            float4 w1 = *(const float4*)(wl + HH);
            float4 w2 = *(const float4*)(wl + 2 * HH);
            float4 w3 = *(const float4*)(wl + 3 * HH);
            a0 += w0.x*s4.x + w1.x*s4.y + w2.x*s4.z + w3.x*s4.w;
            a1 += w0.y*s4.x + w1.y*s4.y + w2.y*s4.z + w3.y*s4.w;
            a2 += w0.z*s4.x + w1.z*s4.y + w2.z*s4.z + w3.z*s4.w;
            a3 += w0.w*s4.x + w1.w*s4.y + w2.w*s4.z + w3.w*s4.w;
        }

        *(float4*)&parts[qq * HH + h4] = make_float4(a0, a1, a2, a3);
        __syncthreads();                    // parts complete; st[cur] reads done

        // ---- reduce + update: thread tid owns h = tid
        float sum = parts[tid] + parts[HH + tid] + parts[2 * HH + tid] + parts[3 * HH + tid];
        float pre = sum + pre_val;
        rf = 0.9f * rf + 0.1f * tanhf(pre);
        pre_rate[row + tid] = rf;           // overwrite pre with rate
        stbuf[nxt * HH + tid] = rf;
        __syncthreads();                    // st[nxt] ready; parts reads done
    }
}

// ---------------------------------------------------------------------------
// Readouts: 8 rows per 256-thread block, rows staged in LDS, float4 dots.
// ---------------------------------------------------------------------------
__global__ __launch_bounds__(256) void readout(
    const float* __restrict__ rate_all,
    const float* __restrict__ Wo,  const float* __restrict__ bo,
    const float* __restrict__ Woc, const float* __restrict__ boc,
    float* __restrict__ out, float* __restrict__ outc)
{
    __shared__ float rbuf[8][HH];
    const int tid  = threadIdx.x;
    const size_t row0 = (size_t)blockIdx.x * 8;

    for (int i = tid; i < 8 * (HH / 4); i += 256) {
        int r = i >> 7, c = (i & 127) * 4;
        *(float4*)&rbuf[r][c] = *(const float4*)&rate_all[(row0 + r) * HH + c];
    }
    __syncthreads();

    {
        int r = tid >> 5, o = tid & 31;
        const float* w = Wo + (size_t)o * HH;
        float acc = 0.f;
        #pragma unroll 4
        for (int h = 0; h < HH; h += 4) {
            float4 rv = *(const float4*)&rbuf[r][h];
            float4 wv = *(const float4*)&w[h];
            acc += rv.x * wv.x + rv.y * wv.y + rv.z * wv.z + rv.w * wv.w;
        }
        out[(row0 + r) * OO + o] = acc + bo[o];
    }
    if (tid < 64) {
        int r = tid >> 3, oc = tid & 7;
        const float* w = Woc + (size_t)oc * HH;
        float acc = 0.f;
        #pragma unroll 4
        for (int h = 0; h < HH; h += 4) {
            float4 rv = *(const float4*)&rbuf[r][h];
            float4 wv = *(const float4*)&w[h];
            acc += rv.x * wv.x + rv.y * wv.y + rv.z * wv.z + rv.w * wv.w;
        }
        outc[(row0 + r) * OCC + oc] = acc + boc[oc];
    }
}

// ---------------------------------------------------------------------------
extern "C" void kernel_launch(void* const* d_in, const int* in_sizes, int n_in,
                              void* d_out, int out_size, void* d_ws, size_t ws_size,
                              hipStream_t stream)
{
    const float* x     = (const float*)d_in[0];
    const float* rate0 = (const float*)d_in[1];
    const float* noise = (const float*)d_in[2];
    const float* Wi    = (const float*)d_in[3];
    const float* bi    = (const float*)d_in[4];
    const float* Wh    = (const float*)d_in[5];
    const float* bh    = (const float*)d_in[6];
    const float* Wo    = (const float*)d_in[7];
    const float* bo    = (const float*)d_in[8];
    const float* Woc   = (const float*)d_in[9];
    const float* boc   = (const float*)d_in[10];

    float* out   = (float*)d_out;
    float* rateb = out + RATE_OFF;          // pre, then rate
    float* Wcat  = (float*)d_ws;            // 512*512 fp32 = 1 MB

    // idempotent, value-deterministic host-side attribute (not a stream op)
    hipFuncSetAttribute((const void*)rnn_scan6,
                        hipFuncAttributeMaxDynamicSharedMemorySize,
                        LDS_FLOATS * sizeof(float));

    pack_weights<<<HH * HH / 256, 256, 0, stream>>>(Wh, Wcat);
    prefold<<<TT * BB / 8, 512, 0, stream>>>(x, noise, Wi, bi, bh, rateb);
    rnn_scan6<<<BB, 512, LDS_FLOATS * sizeof(float), stream>>>(rate0, Wcat, rateb);
    readout<<<TT * BB / 8, 256, 0, stream>>>(rateb, Wo, bo, Woc, boc,
                                             out, out + OUT1_OFF);
}